// Round 16
// baseline (406.155 us; speedup 1.0000x reference)
//
#include <hip/hip_runtime.h>
#include <hip/hip_bf16.h>

// Problem constants (B=32, N=256, K=8, D=1024, OUT=1024, HID=2048)
#define ROWS   8192      // B*N
#define DIM    1024      // D
#define XCOLS  3072      // 3*D
#define OUTC   1024
#define HIDC   2048
#define EPS    1e-5f

typedef __attribute__((ext_vector_type(8))) short bf16x8;   // 8 bf16 (4 VGPRs)
typedef __attribute__((ext_vector_type(4))) float f32x4;

#define GLOBAL_AS __attribute__((address_space(1)))
#define LDS_AS    __attribute__((address_space(3)))

__device__ __forceinline__ void gll16(const void* g, void* l) {
    // async global->LDS, 16B per lane; LDS dest = wave-uniform base + lane*16
    __builtin_amdgcn_global_load_lds((const GLOBAL_AS void*)g, (LDS_AS void*)l, 16, 0, 0);
}

__device__ __forceinline__ short f2b(float f) {
    __hip_bfloat16 h = __float2bfloat16(f);
    return *reinterpret_cast<short*>(&h);
}
__device__ __forceinline__ float b2f(short s) {
    unsigned u = ((unsigned)(unsigned short)s) << 16;
    return __uint_as_float(u);
}

// ---------------------------------------------------------------------------
// Merged prep (one launch, overlapped): blocks [0,8192) do build_x;
// blocks [8192,15360) do the three weight transposes (f32 -> bf16, K-major).
// Both are memory-bound and independent -> true overlap in one dispatch.
// ---------------------------------------------------------------------------
__global__ __launch_bounds__(256) void prep(
    const float* __restrict__ selfv, const float* __restrict__ nb,
    const float* __restrict__ mask, __hip_bfloat16* __restrict__ xb,
    const float* __restrict__ Wa, __hip_bfloat16* __restrict__ WaT,
    const float* __restrict__ W1, __hip_bfloat16* __restrict__ W1T,
    const float* __restrict__ W2, __hip_bfloat16* __restrict__ W2T)
{
    int tid = threadIdx.x;
    if (blockIdx.x < ROWS) {
        // ---- build_x ----
        int r = blockIdx.x;
        __shared__ float ms[8];
        if (tid < 8) ms[tid] = mask[r * 8 + tid];
        __syncthreads();

        __hip_bfloat16* xr = xb + (size_t)r * XCOLS;
        {
            float4 v = ((const float4*)(selfv + (size_t)r * DIM))[tid];
            short4 o;
            o.x = f2b(v.x); o.y = f2b(v.y); o.z = f2b(v.z); o.w = f2b(v.w);
            *(short4*)&xr[tid * 4] = o;
        }
        const float4* nbase = (const float4*)(nb + (size_t)r * 8 * 2048);
#pragma unroll
        for (int half = 0; half < 2; ++half) {
            int c4 = half * 256 + tid;
            float4 acc = make_float4(0.f, 0.f, 0.f, 0.f);
#pragma unroll
            for (int k = 0; k < 8; ++k) {
                float4 t = nbase[k * 512 + c4];
                float m = ms[k];
                acc.x += t.x * m; acc.y += t.y * m; acc.z += t.z * m; acc.w += t.w * m;
            }
            short4 o;
            o.x = f2b(acc.x * 0.125f); o.y = f2b(acc.y * 0.125f);
            o.z = f2b(acc.z * 0.125f); o.w = f2b(acc.w * 0.125f);
            *(short4*)&xr[1024 + c4 * 4] = o;
        }
    } else {
        // ---- wtrans3 ----
        int b = blockIdx.x - ROWS;
        const float* W; __hip_bfloat16* Wt; int K, N;
        if (b < 3072)      { W = Wa; Wt = WaT; K = 3072; N = 1024; }
        else if (b < 5120) { W = W1; Wt = W1T; K = 1024; N = 2048; b -= 3072; }
        else               { W = W2; Wt = W2T; K = 2048; N = 1024; b -= 5120; }
        int nxb = N >> 5;
        int n0 = (b % nxb) << 5, k0 = (b / nxb) << 5;

        __shared__ float t[32][33];
        int tx = tid & 31, ty = tid >> 5;   // 32 x 8
#pragma unroll
        for (int i = 0; i < 4; ++i)
            t[ty + i * 8][tx] = W[(size_t)(k0 + ty + i * 8) * N + n0 + tx];
        __syncthreads();
#pragma unroll
        for (int i = 0; i < 4; ++i) {
            int n = ty + i * 8;
            Wt[(size_t)(n0 + n) * K + k0 + tx] = __float2bfloat16(t[tx][n]);
        }
    }
}

// ---------------------------------------------------------------------------
// GEMM: C[M,N] = A[M,K] @ Bt[N,K]^T + bias   (bf16 in, f32 acc)
// 128x128 tile, BK=64, 512 threads = 8 waves (2Mx4N, wave tile 64x32),
// 16x16x32 MFMA, acc[4][2]  (R13 geometry, the best measured).
// R16 change: THREE LDS buffers (96 KB, 1 block/CU) + COUNTED vmcnt(4):
// tiles t+1,t+2 in flight; step t = {ds_read(t%3) || stage((t+2)%3)} ->
// barrier -> lgkm(0) -> setprio 16xMFMA -> vmcnt(4) -> barrier. Loads get
// TWO full K-steps to land vs R13's per-step vmcnt(0) drain (~300-600 cyc
// residual HBM latency per K-step -- the surviving explanation after R9/R10/
// R11/R15 eliminated conflicts/occupancy/ordering/LDS-redundancy).
// Hazards: RAW tile t+1 via trailing vmcnt(4)+barrier (oldest 4 of 8);
// WAR buffer (t+2)%3==(t-1)%3 whose reads finished before step t-1's lgkm0
// + trailing barrier. Tail: vmcnt(0) once staging stops.
// Bank swizzle for 128B rows: phys 16B-chunk p = g ^ (row&7), both sides
// (R9-verified family: SQ_LDS_BANK_CONFLICT 3.8e7 -> 0).
// STATS: per-block-row column partials (sum,sumsq incl. bias) -> pS/pS2[bm][col]
// ---------------------------------------------------------------------------
template <int OUT_BF16, int STATS>
__global__ __launch_bounds__(512) void gemm_bt(
    const short* __restrict__ A, const short* __restrict__ Bt,
    const float* __restrict__ bias, void* __restrict__ Cout,
    float* __restrict__ pS, float* __restrict__ pS2,
    int M, int N, int K, int ntiles)
{
    __shared__ short As[3][128 * 64];   // 3 x 16 KB
    __shared__ short Bs[3][128 * 64];   // 3 x 16 KB   (96 KB total, 1 blk/CU)

    int tid = threadIdx.x;              // 0..511
    int lane = tid & 63;
    int w = tid >> 6;                   // 0..7
    int wm = w >> 2, wn = w & 3;        // 2 x 4 wave grid

    int nbn = N >> 7;
    int rowa = (wm << 6) + (lane & 15);             // A local row (+m*16, m<4)
    int rowb = (wn << 5) + (lane & 15);             // B local row (+n*16, n<2)
    // ds_read swizzle: global chunk g = (lane>>4) | (ks<<2); row&7 == lane&7
    // (row-block offsets are multiples of 16). phys = g ^ (lane&7).
    int cswz0 = (((lane >> 4) ^ (lane & 7)) << 3);          // ks=0
    int cswz1 = ((((lane >> 4) | 4) ^ (lane & 7)) << 3);    // ks=1
    int lofs = w << 9;                  // wave's 64-slot staging region
    // staging: thread stages slots tid and tid+512 per matrix.
    // slot s: row s>>3, phys chunk s&7 -> source global chunk (s&7)^((s>>3)&7)
    int c0 = (((tid & 7) ^ ((tid >> 3) & 7)) << 3);

    for (int tix = blockIdx.x; tix < ntiles; tix += gridDim.x) {
        // XCD swizzle on tile index (ntiles % 8 == 0 here)
        int swz = (tix & 7) * (ntiles >> 3) + (tix >> 3);
        int bm = swz / nbn, bn = swz % nbn;
        int brow = bm << 7, bcol = bn << 7;

        f32x4 acc[4][2] = {};

        const short* gA0 = A + (size_t)(brow + (tid >> 3)) * K + c0;
        const short* gA1 = gA0 + (size_t)64 * K;
        const short* gB0 = Bt + (size_t)(bcol + (tid >> 3)) * K + c0;
        const short* gB1 = gB0 + (size_t)64 * K;

#define STAGE(buf, kk)                                  \
    do {                                                \
        const int buf_ = (buf);                         \
        const int kk_  = (kk);                          \
        gll16(gA0 + kk_, &As[buf_][lofs]);              \
        gll16(gA1 + kk_, &As[buf_][4096 + lofs]);       \
        gll16(gB0 + kk_, &Bs[buf_][lofs]);              \
        gll16(gB1 + kk_, &Bs[buf_][4096 + lofs]);       \
    } while (0)

#define KSTEP(cur, DOSTAGE, SBUF, KKN)                                     \
    do {                                                                   \
        bf16x8 a[4][2], b[2][2];                                           \
        const short* ab = &As[cur][0];                                     \
        const short* bb = &Bs[cur][0];                                     \
        _Pragma("unroll")                                                  \
        for (int m = 0; m < 4; ++m) {                                      \
            int ro = (rowa + (m << 4)) << 6;                               \
            a[m][0] = *(const bf16x8*)&ab[ro + cswz0];                     \
            a[m][1] = *(const bf16x8*)&ab[ro + cswz1];                     \
        }                                                                  \
        _Pragma("unroll")                                                  \
        for (int n = 0; n < 2; ++n) {                                      \
            int ro = (rowb + (n << 4)) << 6;                               \
            b[n][0] = *(const bf16x8*)&bb[ro + cswz0];                     \
            b[n][1] = *(const bf16x8*)&bb[ro + cswz1];                     \
        }                                                                  \
        if (DOSTAGE) STAGE(SBUF, KKN);                                     \
        __builtin_amdgcn_s_barrier();                                      \
        asm volatile("s_waitcnt lgkmcnt(0)" ::: "memory");                 \
        __builtin_amdgcn_s_setprio(1);                                     \
        _Pragma("unroll")                                                  \
        for (int ks = 0; ks < 2; ++ks) {                                   \
            _Pragma("unroll")                                              \
            for (int m = 0; m < 4; ++m) {                                  \
                _Pragma("unroll")                                          \
                for (int n = 0; n < 2; ++n)                                \
                    acc[m][n] = __builtin_amdgcn_mfma_f32_16x16x32_bf16(   \
                        a[m][ks], b[n][ks], acc[m][n], 0, 0, 0);           \
            }                                                              \
        }                                                                  \
        __builtin_amdgcn_s_setprio(0);                                     \
        if (DOSTAGE) { asm volatile("s_waitcnt vmcnt(4)" ::: "memory"); }  \
        else         { asm volatile("s_waitcnt vmcnt(0)" ::: "memory"); }  \
        __builtin_amdgcn_s_barrier();                                      \
    } while (0)

        int nk = K >> 6;               // 48 / 16 / 32 here (always >= 3)

        // prologue: tiles 0,1 staged; tile 0 proven landed (tile 1 in flight)
        STAGE(0, 0);
        STAGE(1, 64);
        asm volatile("s_waitcnt vmcnt(4)" ::: "memory");
        __builtin_amdgcn_s_barrier();

        for (int i = 0; i < nk; ++i) {
            int cur = i % 3;
            int sb = (i + 2) % 3;
            KSTEP(cur, (i + 2 < nk), sb, ((i + 2) << 6));
        }
#undef KSTEP
#undef STAGE

        // epilogue: C/D layout col=lane&15, row=(lane>>4)*4+reg
        int crow0 = brow + (wm << 6) + ((lane >> 4) << 2);
        int ccol0 = bcol + (wn << 5) + (lane & 15);
        float cs[2] = {0.f, 0.f}, cs2[2] = {0.f, 0.f};
#pragma unroll
        for (int m = 0; m < 4; ++m) {
#pragma unroll
            for (int n = 0; n < 2; ++n) {
                int col = ccol0 + n * 16;
                float bv = bias[col];
#pragma unroll
                for (int r = 0; r < 4; ++r) {
                    int row = crow0 + m * 16 + r;
                    float v = acc[m][n][r] + bv;
                    if (OUT_BF16) {
                        ((__hip_bfloat16*)Cout)[(size_t)row * N + col] = __float2bfloat16(v);
                    } else {
                        ((float*)Cout)[(size_t)row * N + col] = v;
                    }
                    if (STATS) { cs[n] += v; cs2[n] += v * v; }
                }
            }
        }

        if (STATS) {
            float* sP = (float*)&As[0][0];   // reuse LDS (fenced by loop barrier)
#pragma unroll
            for (int n = 0; n < 2; ++n) {
                float s = cs[n], s2 = cs2[n];
                s  += __shfl_xor(s, 16);  s  += __shfl_xor(s, 32);
                s2 += __shfl_xor(s2, 16); s2 += __shfl_xor(s2, 32);
                if ((lane >> 4) == 0) {
                    int c = (wn << 5) + (n << 4) + (lane & 15);   // 0..127
                    sP[wm * 128 + c] = s;
                    sP[256 + wm * 128 + c] = s2;
                }
            }
            __syncthreads();
            if (tid < 128) {
                float s = sP[tid] + sP[128 + tid];
                float s2 = sP[256 + tid] + sP[384 + tid];
                pS [(size_t)bm * N + bcol + tid] = s;
                pS2[(size_t)bm * N + bcol + tid] = s2;
            }
            __syncthreads();   // protect sP before next tile's STAGE
        }
    }
}

// ---------------------------------------------------------------------------
// BN stats reduce: 64 row-chunk partials -> per-column scale/shift
// ---------------------------------------------------------------------------
__global__ __launch_bounds__(256) void bn_stats2(
    const float* __restrict__ pS, const float* __restrict__ pS2,
    const float* __restrict__ g, const float* __restrict__ be,
    float* __restrict__ scale, float* __restrict__ shift, int ncols)
{
    int col = blockIdx.x * 256 + threadIdx.x;
    float s = 0.f, s2 = 0.f;
#pragma unroll
    for (int j = 0; j < 64; ++j) {
        s += pS[j * ncols + col];
        s2 += pS2[j * ncols + col];
    }
    float mu = s * (1.f / 8192.f);
    float var = s2 * (1.f / 8192.f) - mu * mu;
    float rs = rsqrtf(var + EPS);
    float sc = g[col] * rs;
    scale[col] = sc;
    shift[col] = be[col] - mu * sc;
}

// BN apply + ReLU, bf16 in -> bf16 out (hidden activation)
__global__ __launch_bounds__(256) void bn_apply_b2b(
    const short* __restrict__ t, const float* __restrict__ scale,
    const float* __restrict__ shift, short* __restrict__ out, int ncols)
{
    size_t i8 = (size_t)blockIdx.x * 256 + threadIdx.x;
    int col0 = (int)((i8 * 8) % ncols);
    bf16x8 v = ((const bf16x8*)t)[i8];
    bf16x8 o;
#pragma unroll
    for (int j = 0; j < 8; ++j) {
        float f = fmaxf(b2f(v[j]) * scale[col0 + j] + shift[col0 + j], 0.f);
        o[j] = f2b(f);
    }
    ((bf16x8*)out)[i8] = o;
}

// BN apply + ReLU, bf16 in -> f32 out (final, into d_out)
__global__ __launch_bounds__(256) void bn_apply_b2f(
    const short* __restrict__ t, const float* __restrict__ scale,
    const float* __restrict__ shift, float* __restrict__ out, int ncols)
{
    size_t i8 = (size_t)blockIdx.x * 256 + threadIdx.x;
    int col0 = (int)((i8 * 8) % ncols);
    bf16x8 v = ((const bf16x8*)t)[i8];
    float4 o0, o1;
    o0.x = fmaxf(b2f(v[0]) * scale[col0 + 0] + shift[col0 + 0], 0.f);
    o0.y = fmaxf(b2f(v[1]) * scale[col0 + 1] + shift[col0 + 1], 0.f);
    o0.z = fmaxf(b2f(v[2]) * scale[col0 + 2] + shift[col0 + 2], 0.f);
    o0.w = fmaxf(b2f(v[3]) * scale[col0 + 3] + shift[col0 + 3], 0.f);
    o1.x = fmaxf(b2f(v[4]) * scale[col0 + 4] + shift[col0 + 4], 0.f);
    o1.y = fmaxf(b2f(v[5]) * scale[col0 + 5] + shift[col0 + 5], 0.f);
    o1.z = fmaxf(b2f(v[6]) * scale[col0 + 6] + shift[col0 + 6], 0.f);
    o1.w = fmaxf(b2f(v[7]) * scale[col0 + 7] + shift[col0 + 7], 0.f);
    ((float4*)out)[i8 * 2]     = o0;
    ((float4*)out)[i8 * 2 + 1] = o1;
}

// ---------------------------------------------------------------------------
extern "C" void kernel_launch(void* const* d_in, const int* in_sizes, int n_in,
                              void* d_out, int out_size, void* d_ws, size_t ws_size,
                              hipStream_t stream)
{
    const float* selfv = (const float*)d_in[0];   // [32,256,1024]
    const float* nbv   = (const float*)d_in[1];   // [32,256,8,2048]
    const float* mask  = (const float*)d_in[2];   // [32,256,8,1]
    const float* W_agg = (const float*)d_in[3];   // [3072,1024]
    const float* b_agg = (const float*)d_in[4];   // [1024]
    const float* W1    = (const float*)d_in[5];   // [1024,2048]
    const float* b1    = (const float*)d_in[6];   // [2048]
    const float* g1    = (const float*)d_in[7];
    const float* be1   = (const float*)d_in[8];
    const float* W2    = (const float*)d_in[9];   // [2048,1024]
    const float* b2    = (const float*)d_in[10];
    const float* g2    = (const float*)d_in[11];
    const float* be2   = (const float*)d_in[12];

    char* ws = (char*)d_ws;
    const size_t MiB = 1ull << 20;
    __hip_bfloat16* h    = (__hip_bfloat16*)(ws + 0);          // [8192,1024] bf16, 16 MiB
    __hip_bfloat16* xb   = (__hip_bfloat16*)(ws + 16 * MiB);   // [8192,3072] bf16, 48 MiB
    __hip_bfloat16* t1b  = (__hip_bfloat16*)(ws + 16 * MiB);   // [8192,2048] bf16, 32 MiB
    __hip_bfloat16* h1   = (__hip_bfloat16*)(ws + 80 * MiB);   // [8192,2048] bf16, 32 MiB
    __hip_bfloat16* WaggT= (__hip_bfloat16*)(ws + 112 * MiB);  // [1024,3072] bf16, 6 MiB
    __hip_bfloat16* W1T  = (__hip_bfloat16*)(ws + 118 * MiB);  // [2048,1024] bf16, 4 MiB
    __hip_bfloat16* W2T  = (__hip_bfloat16*)(ws + 122 * MiB);  // [1024,2048] bf16, 4 MiB
    float* pS     = (float*)(ws + 126 * MiB);                   // [64,2048] partials
    float* pS2    = (float*)(ws + 126 * MiB + 512 * 1024);
    float* scale1 = (float*)(ws + 127 * MiB);
    float* shift1 = scale1 + 2048;
    float* scale2 = shift1 + 2048;
    float* shift2 = scale2 + 1024;
    __hip_bfloat16* t2b = h;   // [8192,1024] bf16 (h is dead after GEMM2)

    // merged prep: build_x (blocks 0..8191) + 3 weight transposes (rest)
    prep<<<ROWS + 7168, 256, 0, stream>>>(
        selfv, nbv, mask, xb, W_agg, WaggT, W1, W1T, W2, W2T);

    // GEMM1: h = x @ W_agg + b_agg   (bf16 out, no stats)  [2 tiles/block]
    gemm_bt<1, 0><<<256, 512, 0, stream>>>(
        (const short*)xb, (const short*)WaggT, b_agg, h, nullptr, nullptr,
        ROWS, OUTC, XCOLS, 512);

    // GEMM2: t1b = h @ W1 + b1  (bf16 out + BN1 partials)  [4 tiles/block]
    gemm_bt<1, 1><<<256, 512, 0, stream>>>(
        (const short*)h, (const short*)W1T, b1, t1b, pS, pS2, ROWS, HIDC, OUTC, 1024);

    // BN1 reduce + apply + ReLU -> h1 (bf16)
    bn_stats2<<<HIDC / 256, 256, 0, stream>>>(pS, pS2, g1, be1, scale1, shift1, HIDC);
    bn_apply_b2b<<<(ROWS * HIDC) / 2048, 256, 0, stream>>>(
        (const short*)t1b, scale1, shift1, (short*)h1, HIDC);

    // GEMM3: t2b = h1 @ W2 + b2  (bf16 out + BN2 partials) [2 tiles/block]
    gemm_bt<1, 1><<<256, 512, 0, stream>>>(
        (const short*)h1, (const short*)W2T, b2, t2b, pS, pS2, ROWS, OUTC, HIDC, 512);

    // BN2 reduce + apply + ReLU -> d_out (f32)
    bn_stats2<<<OUTC / 256, 256, 0, stream>>>(pS, pS2, g2, be2, scale2, shift2, OUTC);
    bn_apply_b2f<<<(ROWS * OUTC) / 2048, 256, 0, stream>>>(
        (const short*)t2b, scale2, shift2, (float*)d_out, OUTC);
}

// Round 17
// 368.717 us; speedup vs baseline: 1.1015x; 1.1015x over previous
//
#include <hip/hip_runtime.h>
#include <hip/hip_bf16.h>

// Problem constants (B=32, N=256, K=8, D=1024, OUT=1024, HID=2048)
#define ROWS   8192      // B*N
#define DIM    1024      // D
#define XCOLS  3072      // 3*D
#define OUTC   1024
#define HIDC   2048
#define EPS    1e-5f

typedef __attribute__((ext_vector_type(8))) short bf16x8;   // 8 bf16 (4 VGPRs)
typedef __attribute__((ext_vector_type(4))) float f32x4;

#define GLOBAL_AS __attribute__((address_space(1)))
#define LDS_AS    __attribute__((address_space(3)))

__device__ __forceinline__ void gll16(const void* g, void* l) {
    // async global->LDS, 16B per lane; LDS dest = wave-uniform base + lane*16
    __builtin_amdgcn_global_load_lds((const GLOBAL_AS void*)g, (LDS_AS void*)l, 16, 0, 0);
}

__device__ __forceinline__ short f2b(float f) {
    __hip_bfloat16 h = __float2bfloat16(f);
    return *reinterpret_cast<short*>(&h);
}
__device__ __forceinline__ float b2f(short s) {
    unsigned u = ((unsigned)(unsigned short)s) << 16;
    return __uint_as_float(u);
}

// ---------------------------------------------------------------------------
// Merged prep (one launch, overlapped): blocks [0,8192) do build_x;
// blocks [8192,15360) do the three weight transposes (f32 -> bf16, K-major).
// Both memory-bound and independent -> wtrans backfills CUs while build_x
// streams (kept from R16; the R16 regression was the GEMM change, reverted).
// ---------------------------------------------------------------------------
__global__ __launch_bounds__(256) void prep(
    const float* __restrict__ selfv, const float* __restrict__ nb,
    const float* __restrict__ mask, __hip_bfloat16* __restrict__ xb,
    const float* __restrict__ Wa, __hip_bfloat16* __restrict__ WaT,
    const float* __restrict__ W1, __hip_bfloat16* __restrict__ W1T,
    const float* __restrict__ W2, __hip_bfloat16* __restrict__ W2T)
{
    int tid = threadIdx.x;
    if (blockIdx.x < ROWS) {
        // ---- build_x ----
        int r = blockIdx.x;
        __shared__ float ms[8];
        if (tid < 8) ms[tid] = mask[r * 8 + tid];
        __syncthreads();

        __hip_bfloat16* xr = xb + (size_t)r * XCOLS;
        {
            float4 v = ((const float4*)(selfv + (size_t)r * DIM))[tid];
            short4 o;
            o.x = f2b(v.x); o.y = f2b(v.y); o.z = f2b(v.z); o.w = f2b(v.w);
            *(short4*)&xr[tid * 4] = o;
        }
        const float4* nbase = (const float4*)(nb + (size_t)r * 8 * 2048);
#pragma unroll
        for (int half = 0; half < 2; ++half) {
            int c4 = half * 256 + tid;
            float4 acc = make_float4(0.f, 0.f, 0.f, 0.f);
#pragma unroll
            for (int k = 0; k < 8; ++k) {
                float4 t = nbase[k * 512 + c4];
                float m = ms[k];
                acc.x += t.x * m; acc.y += t.y * m; acc.z += t.z * m; acc.w += t.w * m;
            }
            short4 o;
            o.x = f2b(acc.x * 0.125f); o.y = f2b(acc.y * 0.125f);
            o.z = f2b(acc.z * 0.125f); o.w = f2b(acc.w * 0.125f);
            *(short4*)&xr[1024 + c4 * 4] = o;
        }
    } else {
        // ---- wtrans3 ----
        int b = blockIdx.x - ROWS;
        const float* W; __hip_bfloat16* Wt; int K, N;
        if (b < 3072)      { W = Wa; Wt = WaT; K = 3072; N = 1024; }
        else if (b < 5120) { W = W1; Wt = W1T; K = 1024; N = 2048; b -= 3072; }
        else               { W = W2; Wt = W2T; K = 2048; N = 1024; b -= 5120; }
        int nxb = N >> 5;
        int n0 = (b % nxb) << 5, k0 = (b / nxb) << 5;

        __shared__ float t[32][33];
        int tx = tid & 31, ty = tid >> 5;   // 32 x 8
#pragma unroll
        for (int i = 0; i < 4; ++i)
            t[ty + i * 8][tx] = W[(size_t)(k0 + ty + i * 8) * N + n0 + tx];
        __syncthreads();
#pragma unroll
        for (int i = 0; i < 4; ++i) {
            int n = ty + i * 8;
            Wt[(size_t)(n0 + n) * K + k0 + tx] = __float2bfloat16(t[tx][n]);
        }
    }
}

// ---------------------------------------------------------------------------
// GEMM: C[M,N] = A[M,K] @ Bt[N,K]^T + bias   (bf16 in, f32 acc)
// R13 GEMM, verbatim (best measured: 377.4us total). 128x128 tile, BK=64,
// 512 threads = 8 waves (2Mx4N, wave tile 64x32), 16x16x32 MFMA, acc[4][2].
// TWO LDS buffers of [128][64] (64 KB -> 2 blocks/CU, 16 waves/CU).
// K-step (stage-early): {issue 12 ds_read || issue stage(t+1)} -> s_barrier
// -> lgkmcnt(0) -> setprio(1) 16xMFMA setprio(0) -> vmcnt(0) -> s_barrier.
// [R16's 3-buffer/counted-vmcnt variant at 1 blk/CU regressed: this
//  structure lives off inter-block TLP, not intra-block pipeline depth.]
// Bank swizzle for 128B rows: phys 16B-chunk p = g ^ (row&7), both sides
// (R9-verified family: SQ_LDS_BANK_CONFLICT 3.8e7 -> 0).
// STATS: per-block-row column partials (sum,sumsq incl. bias) -> pS/pS2[bm][col]
// ---------------------------------------------------------------------------
template <int OUT_BF16, int STATS>
__global__ __launch_bounds__(512) void gemm_bt(
    const short* __restrict__ A, const short* __restrict__ Bt,
    const float* __restrict__ bias, void* __restrict__ Cout,
    float* __restrict__ pS, float* __restrict__ pS2,
    int M, int N, int K, int ntiles)
{
    __shared__ short As[2][128 * 64];   // 2 x 16 KB
    __shared__ short Bs[2][128 * 64];   // 2 x 16 KB   (64 KB total)

    int tid = threadIdx.x;              // 0..511
    int lane = tid & 63;
    int w = tid >> 6;                   // 0..7
    int wm = w >> 2, wn = w & 3;        // 2 x 4 wave grid

    int nbn = N >> 7;
    int rowa = (wm << 6) + (lane & 15);             // A local row (+m*16, m<4)
    int rowb = (wn << 5) + (lane & 15);             // B local row (+n*16, n<2)
    // ds_read swizzle: global chunk g = (lane>>4) | (ks<<2); row&7 == lane&7
    // (row-block offsets are multiples of 16). phys = g ^ (lane&7).
    int cswz0 = (((lane >> 4) ^ (lane & 7)) << 3);          // ks=0
    int cswz1 = ((((lane >> 4) | 4) ^ (lane & 7)) << 3);    // ks=1
    int lofs = w << 9;                  // wave's 64-slot staging region
    // staging: thread stages slots tid and tid+512 per matrix.
    // slot s: row s>>3, phys chunk s&7 -> source global chunk (s&7)^((s>>3)&7)
    int c0 = (((tid & 7) ^ ((tid >> 3) & 7)) << 3);

    for (int tix = blockIdx.x; tix < ntiles; tix += gridDim.x) {
        // XCD swizzle on tile index (ntiles % 8 == 0 here)
        int swz = (tix & 7) * (ntiles >> 3) + (tix >> 3);
        int bm = swz / nbn, bn = swz % nbn;
        int brow = bm << 7, bcol = bn << 7;

        f32x4 acc[4][2] = {};

        const short* gA0 = A + (size_t)(brow + (tid >> 3)) * K + c0;
        const short* gA1 = gA0 + (size_t)64 * K;
        const short* gB0 = Bt + (size_t)(bcol + (tid >> 3)) * K + c0;
        const short* gB1 = gB0 + (size_t)64 * K;

#define STAGE(buf, kk)                                  \
    do {                                                \
        const int buf_ = (buf);                         \
        const int kk_  = (kk);                          \
        gll16(gA0 + kk_, &As[buf_][lofs]);              \
        gll16(gA1 + kk_, &As[buf_][4096 + lofs]);       \
        gll16(gB0 + kk_, &Bs[buf_][lofs]);              \
        gll16(gB1 + kk_, &Bs[buf_][4096 + lofs]);       \
    } while (0)

#define KSTEP(cur, DOSTAGE, SBUF, KKN)                                     \
    do {                                                                   \
        bf16x8 a[4][2], b[2][2];                                           \
        const short* ab = &As[cur][0];                                     \
        const short* bb = &Bs[cur][0];                                     \
        _Pragma("unroll")                                                  \
        for (int m = 0; m < 4; ++m) {                                      \
            int ro = (rowa + (m << 4)) << 6;                               \
            a[m][0] = *(const bf16x8*)&ab[ro + cswz0];                     \
            a[m][1] = *(const bf16x8*)&ab[ro + cswz1];                     \
        }                                                                  \
        _Pragma("unroll")                                                  \
        for (int n = 0; n < 2; ++n) {                                      \
            int ro = (rowb + (n << 4)) << 6;                               \
            b[n][0] = *(const bf16x8*)&bb[ro + cswz0];                     \
            b[n][1] = *(const bf16x8*)&bb[ro + cswz1];                     \
        }                                                                  \
        if (DOSTAGE) STAGE(SBUF, KKN);                                     \
        __builtin_amdgcn_s_barrier();                                      \
        asm volatile("s_waitcnt lgkmcnt(0)" ::: "memory");                 \
        __builtin_amdgcn_s_setprio(1);                                     \
        _Pragma("unroll")                                                  \
        for (int ks = 0; ks < 2; ++ks) {                                   \
            _Pragma("unroll")                                              \
            for (int m = 0; m < 4; ++m) {                                  \
                _Pragma("unroll")                                          \
                for (int n = 0; n < 2; ++n)                                \
                    acc[m][n] = __builtin_amdgcn_mfma_f32_16x16x32_bf16(   \
                        a[m][ks], b[n][ks], acc[m][n], 0, 0, 0);           \
            }                                                              \
        }                                                                  \
        __builtin_amdgcn_s_setprio(0);                                     \
        asm volatile("s_waitcnt vmcnt(0)" ::: "memory");                   \
        __builtin_amdgcn_s_barrier();                                      \
    } while (0)

        int nk = K >> 6;               // 48 / 16 / 32 here (always >= 2)

        // prologue: tile 0 staged and proven landed
        STAGE(0, 0);
        asm volatile("s_waitcnt vmcnt(0)" ::: "memory");
        __builtin_amdgcn_s_barrier();

        for (int i = 0; i < nk; ++i) {
            KSTEP((i & 1), (i + 1 < nk), ((i + 1) & 1), ((i + 1) << 6));
        }
#undef KSTEP
#undef STAGE

        // epilogue: C/D layout col=lane&15, row=(lane>>4)*4+reg
        int crow0 = brow + (wm << 6) + ((lane >> 4) << 2);
        int ccol0 = bcol + (wn << 5) + (lane & 15);
        float cs[2] = {0.f, 0.f}, cs2[2] = {0.f, 0.f};
#pragma unroll
        for (int m = 0; m < 4; ++m) {
#pragma unroll
            for (int n = 0; n < 2; ++n) {
                int col = ccol0 + n * 16;
                float bv = bias[col];
#pragma unroll
                for (int r = 0; r < 4; ++r) {
                    int row = crow0 + m * 16 + r;
                    float v = acc[m][n][r] + bv;
                    if (OUT_BF16) {
                        ((__hip_bfloat16*)Cout)[(size_t)row * N + col] = __float2bfloat16(v);
                    } else {
                        ((float*)Cout)[(size_t)row * N + col] = v;
                    }
                    if (STATS) { cs[n] += v; cs2[n] += v * v; }
                }
            }
        }

        if (STATS) {
            float* sP = (float*)&As[0][0];   // reuse LDS (fenced by loop barrier)
#pragma unroll
            for (int n = 0; n < 2; ++n) {
                float s = cs[n], s2 = cs2[n];
                s  += __shfl_xor(s, 16);  s  += __shfl_xor(s, 32);
                s2 += __shfl_xor(s2, 16); s2 += __shfl_xor(s2, 32);
                if ((lane >> 4) == 0) {
                    int c = (wn << 5) + (n << 4) + (lane & 15);   // 0..127
                    sP[wm * 128 + c] = s;
                    sP[256 + wm * 128 + c] = s2;
                }
            }
            __syncthreads();
            if (tid < 128) {
                float s = sP[tid] + sP[128 + tid];
                float s2 = sP[256 + tid] + sP[384 + tid];
                pS [(size_t)bm * N + bcol + tid] = s;
                pS2[(size_t)bm * N + bcol + tid] = s2;
            }
            __syncthreads();   // protect sP before next tile's STAGE
        }
    }
}

// ---------------------------------------------------------------------------
// BN stats reduce: 64 row-chunk partials -> per-column scale/shift
// ---------------------------------------------------------------------------
__global__ __launch_bounds__(256) void bn_stats2(
    const float* __restrict__ pS, const float* __restrict__ pS2,
    const float* __restrict__ g, const float* __restrict__ be,
    float* __restrict__ scale, float* __restrict__ shift, int ncols)
{
    int col = blockIdx.x * 256 + threadIdx.x;
    float s = 0.f, s2 = 0.f;
#pragma unroll
    for (int j = 0; j < 64; ++j) {
        s += pS[j * ncols + col];
        s2 += pS2[j * ncols + col];
    }
    float mu = s * (1.f / 8192.f);
    float var = s2 * (1.f / 8192.f) - mu * mu;
    float rs = rsqrtf(var + EPS);
    float sc = g[col] * rs;
    scale[col] = sc;
    shift[col] = be[col] - mu * sc;
}

// BN apply + ReLU, bf16 in -> bf16 out (hidden activation)
__global__ __launch_bounds__(256) void bn_apply_b2b(
    const short* __restrict__ t, const float* __restrict__ scale,
    const float* __restrict__ shift, short* __restrict__ out, int ncols)
{
    size_t i8 = (size_t)blockIdx.x * 256 + threadIdx.x;
    int col0 = (int)((i8 * 8) % ncols);
    bf16x8 v = ((const bf16x8*)t)[i8];
    bf16x8 o;
#pragma unroll
    for (int j = 0; j < 8; ++j) {
        float f = fmaxf(b2f(v[j]) * scale[col0 + j] + shift[col0 + j], 0.f);
        o[j] = f2b(f);
    }
    ((bf16x8*)out)[i8] = o;
}

// BN apply + ReLU, bf16 in -> f32 out (final, into d_out)
__global__ __launch_bounds__(256) void bn_apply_b2f(
    const short* __restrict__ t, const float* __restrict__ scale,
    const float* __restrict__ shift, float* __restrict__ out, int ncols)
{
    size_t i8 = (size_t)blockIdx.x * 256 + threadIdx.x;
    int col0 = (int)((i8 * 8) % ncols);
    bf16x8 v = ((const bf16x8*)t)[i8];
    float4 o0, o1;
    o0.x = fmaxf(b2f(v[0]) * scale[col0 + 0] + shift[col0 + 0], 0.f);
    o0.y = fmaxf(b2f(v[1]) * scale[col0 + 1] + shift[col0 + 1], 0.f);
    o0.z = fmaxf(b2f(v[2]) * scale[col0 + 2] + shift[col0 + 2], 0.f);
    o0.w = fmaxf(b2f(v[3]) * scale[col0 + 3] + shift[col0 + 3], 0.f);
    o1.x = fmaxf(b2f(v[4]) * scale[col0 + 4] + shift[col0 + 4], 0.f);
    o1.y = fmaxf(b2f(v[5]) * scale[col0 + 5] + shift[col0 + 5], 0.f);
    o1.z = fmaxf(b2f(v[6]) * scale[col0 + 6] + shift[col0 + 6], 0.f);
    o1.w = fmaxf(b2f(v[7]) * scale[col0 + 7] + shift[col0 + 7], 0.f);
    ((float4*)out)[i8 * 2]     = o0;
    ((float4*)out)[i8 * 2 + 1] = o1;
}

// ---------------------------------------------------------------------------
extern "C" void kernel_launch(void* const* d_in, const int* in_sizes, int n_in,
                              void* d_out, int out_size, void* d_ws, size_t ws_size,
                              hipStream_t stream)
{
    const float* selfv = (const float*)d_in[0];   // [32,256,1024]
    const float* nbv   = (const float*)d_in[1];   // [32,256,8,2048]
    const float* mask  = (const float*)d_in[2];   // [32,256,8,1]
    const float* W_agg = (const float*)d_in[3];   // [3072,1024]
    const float* b_agg = (const float*)d_in[4];   // [1024]
    const float* W1    = (const float*)d_in[5];   // [1024,2048]
    const float* b1    = (const float*)d_in[6];   // [2048]
    const float* g1    = (const float*)d_in[7];
    const float* be1   = (const float*)d_in[8];
    const float* W2    = (const float*)d_in[9];   // [2048,1024]
    const float* b2    = (const float*)d_in[10];
    const float* g2    = (const float*)d_in[11];
    const float* be2   = (const float*)d_in[12];

    char* ws = (char*)d_ws;
    const size_t MiB = 1ull << 20;
    __hip_bfloat16* h    = (__hip_bfloat16*)(ws + 0);          // [8192,1024] bf16, 16 MiB
    __hip_bfloat16* xb   = (__hip_bfloat16*)(ws + 16 * MiB);   // [8192,3072] bf16, 48 MiB
    __hip_bfloat16* t1b  = (__hip_bfloat16*)(ws + 16 * MiB);   // [8192,2048] bf16, 32 MiB
    __hip_bfloat16* h1   = (__hip_bfloat16*)(ws + 80 * MiB);   // [8192,2048] bf16, 32 MiB
    __hip_bfloat16* WaggT= (__hip_bfloat16*)(ws + 112 * MiB);  // [1024,3072] bf16, 6 MiB
    __hip_bfloat16* W1T  = (__hip_bfloat16*)(ws + 118 * MiB);  // [2048,1024] bf16, 4 MiB
    __hip_bfloat16* W2T  = (__hip_bfloat16*)(ws + 122 * MiB);  // [1024,2048] bf16, 4 MiB
    float* pS     = (float*)(ws + 126 * MiB);                   // [64,2048] partials
    float* pS2    = (float*)(ws + 126 * MiB + 512 * 1024);
    float* scale1 = (float*)(ws + 127 * MiB);
    float* shift1 = scale1 + 2048;
    float* scale2 = shift1 + 2048;
    float* shift2 = scale2 + 1024;
    __hip_bfloat16* t2b = h;   // [8192,1024] bf16 (h is dead after GEMM2)

    // merged prep: build_x (blocks 0..8191) + 3 weight transposes (rest)
    prep<<<ROWS + 7168, 256, 0, stream>>>(
        selfv, nbv, mask, xb, W_agg, WaggT, W1, W1T, W2, W2T);

    // GEMM1: h = x @ W_agg + b_agg   (bf16 out, no stats)
    gemm_bt<1, 0><<<512, 512, 0, stream>>>(
        (const short*)xb, (const short*)WaggT, b_agg, h, nullptr, nullptr,
        ROWS, OUTC, XCOLS, 512);

    // GEMM2: t1b = h @ W1 + b1  (bf16 out + BN1 partials)
    gemm_bt<1, 1><<<1024, 512, 0, stream>>>(
        (const short*)h, (const short*)W1T, b1, t1b, pS, pS2, ROWS, HIDC, OUTC, 1024);

    // BN1 reduce + apply + ReLU -> h1 (bf16)
    bn_stats2<<<HIDC / 256, 256, 0, stream>>>(pS, pS2, g1, be1, scale1, shift1, HIDC);
    bn_apply_b2b<<<(ROWS * HIDC) / 2048, 256, 0, stream>>>(
        (const short*)t1b, scale1, shift1, (short*)h1, HIDC);

    // GEMM3: t2b = h1 @ W2 + b2  (bf16 out + BN2 partials)
    gemm_bt<1, 1><<<512, 512, 0, stream>>>(
        (const short*)h1, (const short*)W2T, b2, t2b, pS, pS2, ROWS, OUTC, HIDC, 512);

    // BN2 reduce + apply + ReLU -> d_out (f32)
    bn_stats2<<<OUTC / 256, 256, 0, stream>>>(pS, pS2, g2, be2, scale2, shift2, OUTC);
    bn_apply_b2f<<<(ROWS * OUTC) / 2048, 256, 0, stream>>>(
        (const short*)t2b, scale2, shift2, (float*)d_out, OUTC);
}

// Round 18
// 367.282 us; speedup vs baseline: 1.1058x; 1.0039x over previous
//
#include <hip/hip_runtime.h>
#include <hip/hip_bf16.h>

// Problem constants (B=32, N=256, K=8, D=1024, OUT=1024, HID=2048)
#define ROWS   8192      // B*N
#define DIM    1024      // D
#define XCOLS  3072      // 3*D
#define OUTC   1024
#define HIDC   2048
#define EPS    1e-5f

typedef __attribute__((ext_vector_type(8))) short bf16x8;   // 8 bf16 (4 VGPRs)
typedef __attribute__((ext_vector_type(4))) float f32x4;

#define GLOBAL_AS __attribute__((address_space(1)))
#define LDS_AS    __attribute__((address_space(3)))

__device__ __forceinline__ void gll16(const void* g, void* l) {
    // async global->LDS, 16B per lane; LDS dest = wave-uniform base + lane*16
    __builtin_amdgcn_global_load_lds((const GLOBAL_AS void*)g, (LDS_AS void*)l, 16, 0, 0);
}

__device__ __forceinline__ short f2b(float f) {
    __hip_bfloat16 h = __float2bfloat16(f);
    return *reinterpret_cast<short*>(&h);
}
__device__ __forceinline__ float b2f(short s) {
    unsigned u = ((unsigned)(unsigned short)s) << 16;
    return __uint_as_float(u);
}

// ---------------------------------------------------------------------------
// Merged prep (one launch, overlapped): blocks [0,8192) do build_x;
// blocks [8192,15360) do the three weight transposes (f32 -> bf16, K-major).
// ---------------------------------------------------------------------------
__global__ __launch_bounds__(256) void prep(
    const float* __restrict__ selfv, const float* __restrict__ nb,
    const float* __restrict__ mask, __hip_bfloat16* __restrict__ xb,
    const float* __restrict__ Wa, __hip_bfloat16* __restrict__ WaT,
    const float* __restrict__ W1, __hip_bfloat16* __restrict__ W1T,
    const float* __restrict__ W2, __hip_bfloat16* __restrict__ W2T)
{
    int tid = threadIdx.x;
    if (blockIdx.x < ROWS) {
        // ---- build_x ----
        int r = blockIdx.x;
        __shared__ float ms[8];
        if (tid < 8) ms[tid] = mask[r * 8 + tid];
        __syncthreads();

        __hip_bfloat16* xr = xb + (size_t)r * XCOLS;
        {
            float4 v = ((const float4*)(selfv + (size_t)r * DIM))[tid];
            short4 o;
            o.x = f2b(v.x); o.y = f2b(v.y); o.z = f2b(v.z); o.w = f2b(v.w);
            *(short4*)&xr[tid * 4] = o;
        }
        const float4* nbase = (const float4*)(nb + (size_t)r * 8 * 2048);
#pragma unroll
        for (int half = 0; half < 2; ++half) {
            int c4 = half * 256 + tid;
            float4 acc = make_float4(0.f, 0.f, 0.f, 0.f);
#pragma unroll
            for (int k = 0; k < 8; ++k) {
                float4 t = nbase[k * 512 + c4];
                float m = ms[k];
                acc.x += t.x * m; acc.y += t.y * m; acc.z += t.z * m; acc.w += t.w * m;
            }
            short4 o;
            o.x = f2b(acc.x * 0.125f); o.y = f2b(acc.y * 0.125f);
            o.z = f2b(acc.z * 0.125f); o.w = f2b(acc.w * 0.125f);
            *(short4*)&xr[1024 + c4 * 4] = o;
        }
    } else {
        // ---- wtrans3 ----
        int b = blockIdx.x - ROWS;
        const float* W; __hip_bfloat16* Wt; int K, N;
        if (b < 3072)      { W = Wa; Wt = WaT; K = 3072; N = 1024; }
        else if (b < 5120) { W = W1; Wt = W1T; K = 1024; N = 2048; b -= 3072; }
        else               { W = W2; Wt = W2T; K = 2048; N = 1024; b -= 5120; }
        int nxb = N >> 5;
        int n0 = (b % nxb) << 5, k0 = (b / nxb) << 5;

        __shared__ float t[32][33];
        int tx = tid & 31, ty = tid >> 5;   // 32 x 8
#pragma unroll
        for (int i = 0; i < 4; ++i)
            t[ty + i * 8][tx] = W[(size_t)(k0 + ty + i * 8) * N + n0 + tx];
        __syncthreads();
#pragma unroll
        for (int i = 0; i < 4; ++i) {
            int n = ty + i * 8;
            Wt[(size_t)(n0 + n) * K + k0 + tx] = __float2bfloat16(t[tx][n]);
        }
    }
}

// ---------------------------------------------------------------------------
// GEMM: C[M,N] = A[M,K] @ Bt[N,K]^T + bias   (bf16 in, f32 acc)
// R13 geometry (best measured): 128x128 tile, BK=64, 512 threads = 8 waves
// (2Mx4N, wave tile 64x32), 16x16x32 MFMA, acc[4][2], TWO LDS buffers.
// R18 change: MINIMAL per-K-step sync. Hazard re-audit showed the leading
// s_barrier and the explicit lgkmcnt(0) were redundant: RAW on buffer cur is
// fenced by step t-1's trailing vmcnt(0)+barrier; WAR is safe because every
// wave's ds_reads complete (data-dep lgkm wait before its own MFMAs) before
// it reaches the trailing barrier. Dropping them (a) halves barriers/K-step,
// (b) un-pins the compiler's fine-grained lgkmcnt(N) ds_read<->MFMA
// interleave that the forced lgkmcnt(0) was defeating. The trailing
// sched_barrier(0) pins the barrier point so next-step ds_reads (which read
// OTHER waves' staged rows) can't be scheduled above the s_barrier.
// Bank swizzle for 128B rows: phys 16B-chunk p = g ^ (row&7), both sides
// (R9-verified: SQ_LDS_BANK_CONFLICT 3.8e7 -> 0).
// STATS: per-block-row column partials (sum,sumsq incl. bias) -> pS/pS2[bm][col]
// ---------------------------------------------------------------------------
template <int OUT_BF16, int STATS>
__global__ __launch_bounds__(512) void gemm_bt(
    const short* __restrict__ A, const short* __restrict__ Bt,
    const float* __restrict__ bias, void* __restrict__ Cout,
    float* __restrict__ pS, float* __restrict__ pS2,
    int M, int N, int K, int ntiles)
{
    __shared__ short As[2][128 * 64];   // 2 x 16 KB
    __shared__ short Bs[2][128 * 64];   // 2 x 16 KB   (64 KB total)

    int tid = threadIdx.x;              // 0..511
    int lane = tid & 63;
    int w = tid >> 6;                   // 0..7
    int wm = w >> 2, wn = w & 3;        // 2 x 4 wave grid

    int nbn = N >> 7;
    int rowa = (wm << 6) + (lane & 15);             // A local row (+m*16, m<4)
    int rowb = (wn << 5) + (lane & 15);             // B local row (+n*16, n<2)
    // ds_read swizzle: global chunk g = (lane>>4) | (ks<<2); row&7 == lane&7
    // (row-block offsets are multiples of 16). phys = g ^ (lane&7).
    int cswz0 = (((lane >> 4) ^ (lane & 7)) << 3);          // ks=0
    int cswz1 = ((((lane >> 4) | 4) ^ (lane & 7)) << 3);    // ks=1
    int lofs = w << 9;                  // wave's 64-slot staging region
    // staging: thread stages slots tid and tid+512 per matrix.
    // slot s: row s>>3, phys chunk s&7 -> source global chunk (s&7)^((s>>3)&7)
    int c0 = (((tid & 7) ^ ((tid >> 3) & 7)) << 3);

    for (int tix = blockIdx.x; tix < ntiles; tix += gridDim.x) {
        // XCD swizzle on tile index (ntiles % 8 == 0 here)
        int swz = (tix & 7) * (ntiles >> 3) + (tix >> 3);
        int bm = swz / nbn, bn = swz % nbn;
        int brow = bm << 7, bcol = bn << 7;

        f32x4 acc[4][2] = {};

        const short* gA0 = A + (size_t)(brow + (tid >> 3)) * K + c0;
        const short* gA1 = gA0 + (size_t)64 * K;
        const short* gB0 = Bt + (size_t)(bcol + (tid >> 3)) * K + c0;
        const short* gB1 = gB0 + (size_t)64 * K;

#define STAGE(buf, kk)                                  \
    do {                                                \
        const int buf_ = (buf);                         \
        const int kk_  = (kk);                          \
        gll16(gA0 + kk_, &As[buf_][lofs]);              \
        gll16(gA1 + kk_, &As[buf_][4096 + lofs]);       \
        gll16(gB0 + kk_, &Bs[buf_][lofs]);              \
        gll16(gB1 + kk_, &Bs[buf_][4096 + lofs]);       \
    } while (0)

// Minimal-sync K-step: ds_read issue || stage issue -> MFMA cluster (compiler
// inserts fine-grained lgkmcnt waits) -> vmcnt(0) fence -> s_barrier ->
// sched_barrier(0) (keeps next-step LDS reads below the barrier).
#define KSTEP(cur, DOSTAGE, SBUF, KKN)                                     \
    do {                                                                   \
        bf16x8 a[4][2], b[2][2];                                           \
        const short* ab = &As[cur][0];                                     \
        const short* bb = &Bs[cur][0];                                     \
        _Pragma("unroll")                                                  \
        for (int m = 0; m < 4; ++m) {                                      \
            int ro = (rowa + (m << 4)) << 6;                               \
            a[m][0] = *(const bf16x8*)&ab[ro + cswz0];                     \
            a[m][1] = *(const bf16x8*)&ab[ro + cswz1];                     \
        }                                                                  \
        _Pragma("unroll")                                                  \
        for (int n = 0; n < 2; ++n) {                                      \
            int ro = (rowb + (n << 4)) << 6;                               \
            b[n][0] = *(const bf16x8*)&bb[ro + cswz0];                     \
            b[n][1] = *(const bf16x8*)&bb[ro + cswz1];                     \
        }                                                                  \
        if (DOSTAGE) STAGE(SBUF, KKN);                                     \
        __builtin_amdgcn_s_setprio(1);                                     \
        _Pragma("unroll")                                                  \
        for (int ks = 0; ks < 2; ++ks) {                                   \
            _Pragma("unroll")                                              \
            for (int m = 0; m < 4; ++m) {                                  \
                _Pragma("unroll")                                          \
                for (int n = 0; n < 2; ++n)                                \
                    acc[m][n] = __builtin_amdgcn_mfma_f32_16x16x32_bf16(   \
                        a[m][ks], b[n][ks], acc[m][n], 0, 0, 0);           \
            }                                                              \
        }                                                                  \
        __builtin_amdgcn_s_setprio(0);                                     \
        asm volatile("s_waitcnt vmcnt(0)" ::: "memory");                   \
        __builtin_amdgcn_s_barrier();                                      \
        __builtin_amdgcn_sched_barrier(0);                                 \
    } while (0)

        int nk = K >> 6;               // 48 / 16 / 32 here (always >= 2)

        // prologue: tile 0 staged and proven landed
        STAGE(0, 0);
        asm volatile("s_waitcnt vmcnt(0)" ::: "memory");
        __builtin_amdgcn_s_barrier();
        __builtin_amdgcn_sched_barrier(0);

        for (int i = 0; i < nk; ++i) {
            KSTEP((i & 1), (i + 1 < nk), ((i + 1) & 1), ((i + 1) << 6));
        }
#undef KSTEP
#undef STAGE

        // epilogue: C/D layout col=lane&15, row=(lane>>4)*4+reg
        int crow0 = brow + (wm << 6) + ((lane >> 4) << 2);
        int ccol0 = bcol + (wn << 5) + (lane & 15);
        float cs[2] = {0.f, 0.f}, cs2[2] = {0.f, 0.f};
#pragma unroll
        for (int m = 0; m < 4; ++m) {
#pragma unroll
            for (int n = 0; n < 2; ++n) {
                int col = ccol0 + n * 16;
                float bv = bias[col];
#pragma unroll
                for (int r = 0; r < 4; ++r) {
                    int row = crow0 + m * 16 + r;
                    float v = acc[m][n][r] + bv;
                    if (OUT_BF16) {
                        ((__hip_bfloat16*)Cout)[(size_t)row * N + col] = __float2bfloat16(v);
                    } else {
                        ((float*)Cout)[(size_t)row * N + col] = v;
                    }
                    if (STATS) { cs[n] += v; cs2[n] += v * v; }
                }
            }
        }

        if (STATS) {
            float* sP = (float*)&As[0][0];   // reuse LDS (fenced by loop barrier)
#pragma unroll
            for (int n = 0; n < 2; ++n) {
                float s = cs[n], s2 = cs2[n];
                s  += __shfl_xor(s, 16);  s  += __shfl_xor(s, 32);
                s2 += __shfl_xor(s2, 16); s2 += __shfl_xor(s2, 32);
                if ((lane >> 4) == 0) {
                    int c = (wn << 5) + (n << 4) + (lane & 15);   // 0..127
                    sP[wm * 128 + c] = s;
                    sP[256 + wm * 128 + c] = s2;
                }
            }
            __syncthreads();
            if (tid < 128) {
                float s = sP[tid] + sP[128 + tid];
                float s2 = sP[256 + tid] + sP[384 + tid];
                pS [(size_t)bm * N + bcol + tid] = s;
                pS2[(size_t)bm * N + bcol + tid] = s2;
            }
            __syncthreads();   // protect sP before next tile's STAGE
        }
    }
}

// ---------------------------------------------------------------------------
// BN stats reduce: 64 row-chunk partials -> per-column scale/shift
// ---------------------------------------------------------------------------
__global__ __launch_bounds__(256) void bn_stats2(
    const float* __restrict__ pS, const float* __restrict__ pS2,
    const float* __restrict__ g, const float* __restrict__ be,
    float* __restrict__ scale, float* __restrict__ shift, int ncols)
{
    int col = blockIdx.x * 256 + threadIdx.x;
    float s = 0.f, s2 = 0.f;
#pragma unroll
    for (int j = 0; j < 64; ++j) {
        s += pS[j * ncols + col];
        s2 += pS2[j * ncols + col];
    }
    float mu = s * (1.f / 8192.f);
    float var = s2 * (1.f / 8192.f) - mu * mu;
    float rs = rsqrtf(var + EPS);
    float sc = g[col] * rs;
    scale[col] = sc;
    shift[col] = be[col] - mu * sc;
}

// BN apply + ReLU, bf16 in -> bf16 out (hidden activation)
__global__ __launch_bounds__(256) void bn_apply_b2b(
    const short* __restrict__ t, const float* __restrict__ scale,
    const float* __restrict__ shift, short* __restrict__ out, int ncols)
{
    size_t i8 = (size_t)blockIdx.x * 256 + threadIdx.x;
    int col0 = (int)((i8 * 8) % ncols);
    bf16x8 v = ((const bf16x8*)t)[i8];
    bf16x8 o;
#pragma unroll
    for (int j = 0; j < 8; ++j) {
        float f = fmaxf(b2f(v[j]) * scale[col0 + j] + shift[col0 + j], 0.f);
        o[j] = f2b(f);
    }
    ((bf16x8*)out)[i8] = o;
}

// BN apply + ReLU, bf16 in -> f32 out (final, into d_out)
__global__ __launch_bounds__(256) void bn_apply_b2f(
    const short* __restrict__ t, const float* __restrict__ scale,
    const float* __restrict__ shift, float* __restrict__ out, int ncols)
{
    size_t i8 = (size_t)blockIdx.x * 256 + threadIdx.x;
    int col0 = (int)((i8 * 8) % ncols);
    bf16x8 v = ((const bf16x8*)t)[i8];
    float4 o0, o1;
    o0.x = fmaxf(b2f(v[0]) * scale[col0 + 0] + shift[col0 + 0], 0.f);
    o0.y = fmaxf(b2f(v[1]) * scale[col0 + 1] + shift[col0 + 1], 0.f);
    o0.z = fmaxf(b2f(v[2]) * scale[col0 + 2] + shift[col0 + 2], 0.f);
    o0.w = fmaxf(b2f(v[3]) * scale[col0 + 3] + shift[col0 + 3], 0.f);
    o1.x = fmaxf(b2f(v[4]) * scale[col0 + 4] + shift[col0 + 4], 0.f);
    o1.y = fmaxf(b2f(v[5]) * scale[col0 + 5] + shift[col0 + 5], 0.f);
    o1.z = fmaxf(b2f(v[6]) * scale[col0 + 6] + shift[col0 + 6], 0.f);
    o1.w = fmaxf(b2f(v[7]) * scale[col0 + 7] + shift[col0 + 7], 0.f);
    ((float4*)out)[i8 * 2]     = o0;
    ((float4*)out)[i8 * 2 + 1] = o1;
}

// ---------------------------------------------------------------------------
extern "C" void kernel_launch(void* const* d_in, const int* in_sizes, int n_in,
                              void* d_out, int out_size, void* d_ws, size_t ws_size,
                              hipStream_t stream)
{
    const float* selfv = (const float*)d_in[0];   // [32,256,1024]
    const float* nbv   = (const float*)d_in[1];   // [32,256,8,2048]
    const float* mask  = (const float*)d_in[2];   // [32,256,8,1]
    const float* W_agg = (const float*)d_in[3];   // [3072,1024]
    const float* b_agg = (const float*)d_in[4];   // [1024]
    const float* W1    = (const float*)d_in[5];   // [1024,2048]
    const float* b1    = (const float*)d_in[6];   // [2048]
    const float* g1    = (const float*)d_in[7];
    const float* be1   = (const float*)d_in[8];
    const float* W2    = (const float*)d_in[9];   // [2048,1024]
    const float* b2    = (const float*)d_in[10];
    const float* g2    = (const float*)d_in[11];
    const float* be2   = (const float*)d_in[12];

    char* ws = (char*)d_ws;
    const size_t MiB = 1ull << 20;
    __hip_bfloat16* h    = (__hip_bfloat16*)(ws + 0);          // [8192,1024] bf16, 16 MiB
    __hip_bfloat16* xb   = (__hip_bfloat16*)(ws + 16 * MiB);   // [8192,3072] bf16, 48 MiB
    __hip_bfloat16* t1b  = (__hip_bfloat16*)(ws + 16 * MiB);   // [8192,2048] bf16, 32 MiB
    __hip_bfloat16* h1   = (__hip_bfloat16*)(ws + 80 * MiB);   // [8192,2048] bf16, 32 MiB
    __hip_bfloat16* WaggT= (__hip_bfloat16*)(ws + 112 * MiB);  // [1024,3072] bf16, 6 MiB
    __hip_bfloat16* W1T  = (__hip_bfloat16*)(ws + 118 * MiB);  // [2048,1024] bf16, 4 MiB
    __hip_bfloat16* W2T  = (__hip_bfloat16*)(ws + 122 * MiB);  // [1024,2048] bf16, 4 MiB
    float* pS     = (float*)(ws + 126 * MiB);                   // [64,2048] partials
    float* pS2    = (float*)(ws + 126 * MiB + 512 * 1024);
    float* scale1 = (float*)(ws + 127 * MiB);
    float* shift1 = scale1 + 2048;
    float* scale2 = shift1 + 2048;
    float* shift2 = scale2 + 1024;
    __hip_bfloat16* t2b = h;   // [8192,1024] bf16 (h is dead after GEMM2)

    // merged prep: build_x (blocks 0..8191) + 3 weight transposes (rest)
    prep<<<ROWS + 7168, 256, 0, stream>>>(
        selfv, nbv, mask, xb, W_agg, WaggT, W1, W1T, W2, W2T);

    // GEMM1: h = x @ W_agg + b_agg   (bf16 out, no stats)
    gemm_bt<1, 0><<<512, 512, 0, stream>>>(
        (const short*)xb, (const short*)WaggT, b_agg, h, nullptr, nullptr,
        ROWS, OUTC, XCOLS, 512);

    // GEMM2: t1b = h @ W1 + b1  (bf16 out + BN1 partials)
    gemm_bt<1, 1><<<1024, 512, 0, stream>>>(
        (const short*)h, (const short*)W1T, b1, t1b, pS, pS2, ROWS, HIDC, OUTC, 1024);

    // BN1 reduce + apply + ReLU -> h1 (bf16)
    bn_stats2<<<HIDC / 256, 256, 0, stream>>>(pS, pS2, g1, be1, scale1, shift1, HIDC);
    bn_apply_b2b<<<(ROWS * HIDC) / 2048, 256, 0, stream>>>(
        (const short*)t1b, scale1, shift1, (short*)h1, HIDC);

    // GEMM3: t2b = h1 @ W2 + b2  (bf16 out + BN2 partials)
    gemm_bt<1, 1><<<512, 512, 0, stream>>>(
        (const short*)h1, (const short*)W2T, b2, t2b, pS, pS2, ROWS, OUTC, HIDC, 512);

    // BN2 reduce + apply + ReLU -> d_out (f32)
    bn_stats2<<<OUTC / 256, 256, 0, stream>>>(pS, pS2, g2, be2, scale2, shift2, OUTC);
    bn_apply_b2f<<<(ROWS * OUTC) / 2048, 256, 0, stream>>>(
        (const short*)t2b, scale2, shift2, (float*)d_out, OUTC);
}

// Round 19
// 364.648 us; speedup vs baseline: 1.1138x; 1.0072x over previous
//
#include <hip/hip_runtime.h>
#include <hip/hip_bf16.h>

// Problem constants (B=32, N=256, K=8, D=1024, OUT=1024, HID=2048)
#define ROWS   8192      // B*N
#define DIM    1024      // D
#define XCOLS  3072      // 3*D
#define OUTC   1024
#define HIDC   2048
#define EPS    1e-5f

typedef __attribute__((ext_vector_type(8))) short bf16x8;   // 8 bf16 (4 VGPRs)
typedef __attribute__((ext_vector_type(4))) float f32x4;

#define GLOBAL_AS __attribute__((address_space(1)))
#define LDS_AS    __attribute__((address_space(3)))

__device__ __forceinline__ void gll16(const void* g, void* l) {
    // async global->LDS, 16B per lane; LDS dest = wave-uniform base + lane*16
    __builtin_amdgcn_global_load_lds((const GLOBAL_AS void*)g, (LDS_AS void*)l, 16, 0, 0);
}

__device__ __forceinline__ short f2b(float f) {
    __hip_bfloat16 h = __float2bfloat16(f);
    return *reinterpret_cast<short*>(&h);
}
__device__ __forceinline__ float b2f(short s) {
    unsigned u = ((unsigned)(unsigned short)s) << 16;
    return __uint_as_float(u);
}

// ---------------------------------------------------------------------------
// Merged prep (one launch, overlapped): blocks [0,8192) do build_x;
// blocks [8192,15360) do the three weight transposes (f32 -> bf16, K-major).
// ---------------------------------------------------------------------------
__global__ __launch_bounds__(256) void prep(
    const float* __restrict__ selfv, const float* __restrict__ nb,
    const float* __restrict__ mask, __hip_bfloat16* __restrict__ xb,
    const float* __restrict__ Wa, __hip_bfloat16* __restrict__ WaT,
    const float* __restrict__ W1, __hip_bfloat16* __restrict__ W1T,
    const float* __restrict__ W2, __hip_bfloat16* __restrict__ W2T)
{
    int tid = threadIdx.x;
    if (blockIdx.x < ROWS) {
        // ---- build_x ----
        int r = blockIdx.x;
        __shared__ float ms[8];
        if (tid < 8) ms[tid] = mask[r * 8 + tid];
        __syncthreads();

        __hip_bfloat16* xr = xb + (size_t)r * XCOLS;
        {
            float4 v = ((const float4*)(selfv + (size_t)r * DIM))[tid];
            short4 o;
            o.x = f2b(v.x); o.y = f2b(v.y); o.z = f2b(v.z); o.w = f2b(v.w);
            *(short4*)&xr[tid * 4] = o;
        }
        const float4* nbase = (const float4*)(nb + (size_t)r * 8 * 2048);
#pragma unroll
        for (int half = 0; half < 2; ++half) {
            int c4 = half * 256 + tid;
            float4 acc = make_float4(0.f, 0.f, 0.f, 0.f);
#pragma unroll
            for (int k = 0; k < 8; ++k) {
                float4 t = nbase[k * 512 + c4];
                float m = ms[k];
                acc.x += t.x * m; acc.y += t.y * m; acc.z += t.z * m; acc.w += t.w * m;
            }
            short4 o;
            o.x = f2b(acc.x * 0.125f); o.y = f2b(acc.y * 0.125f);
            o.z = f2b(acc.z * 0.125f); o.w = f2b(acc.w * 0.125f);
            *(short4*)&xr[1024 + c4 * 4] = o;
        }
    } else {
        // ---- wtrans3 ----
        int b = blockIdx.x - ROWS;
        const float* W; __hip_bfloat16* Wt; int K, N;
        if (b < 3072)      { W = Wa; Wt = WaT; K = 3072; N = 1024; }
        else if (b < 5120) { W = W1; Wt = W1T; K = 1024; N = 2048; b -= 3072; }
        else               { W = W2; Wt = W2T; K = 2048; N = 1024; b -= 5120; }
        int nxb = N >> 5;
        int n0 = (b % nxb) << 5, k0 = (b / nxb) << 5;

        __shared__ float t[32][33];
        int tx = tid & 31, ty = tid >> 5;   // 32 x 8
#pragma unroll
        for (int i = 0; i < 4; ++i)
            t[ty + i * 8][tx] = W[(size_t)(k0 + ty + i * 8) * N + n0 + tx];
        __syncthreads();
#pragma unroll
        for (int i = 0; i < 4; ++i) {
            int n = ty + i * 8;
            Wt[(size_t)(n0 + n) * K + k0 + tx] = __float2bfloat16(t[tx][n]);
        }
    }
}

// ---------------------------------------------------------------------------
// GEMM: C[M,N] = A[M,K] @ Bt[N,K]^T + bias   (bf16 in, f32 acc)
// R18 loop (best measured): 128x128 tile, BK=64, 512 threads = 8 waves
// (2Mx4N, wave tile 64x32), 16x16x32 MFMA, acc[4][2], TWO LDS buffers,
// minimal-sync K-step {ds_read||stage -> MFMA -> vmcnt(0) -> barrier}.
// R19 change: COALESCED EPILOGUE. Old: 32 scalar 2B stores/thread (4rowx16col
// scatter, 32B granules). New: wave-private 4KB LDS transpose (ds_write_b16,
// no cross-wave sharing -> no barrier), lgkm(0), re-read row-major, store
// 4 x 16B/lane (wave = 16 rows x 64B contiguous). One __syncthreads added
// before sP / next-tile STAGE reuse (WAR on the tp regions).
// Bank swizzle for 128B rows: phys 16B-chunk p = g ^ (row&7), both sides
// (R9-verified: SQ_LDS_BANK_CONFLICT 3.8e7 -> 0).
// STATS: per-block-row column partials (sum,sumsq incl. bias) -> pS/pS2[bm][col]
// ---------------------------------------------------------------------------
template <int OUT_BF16, int STATS>
__global__ __launch_bounds__(512) void gemm_bt(
    const short* __restrict__ A, const short* __restrict__ Bt,
    const float* __restrict__ bias, void* __restrict__ Cout,
    float* __restrict__ pS, float* __restrict__ pS2,
    int M, int N, int K, int ntiles)
{
    __shared__ short As[2][128 * 64];   // 2 x 16 KB
    __shared__ short Bs[2][128 * 64];   // 2 x 16 KB   (64 KB total)

    int tid = threadIdx.x;              // 0..511
    int lane = tid & 63;
    int w = tid >> 6;                   // 0..7
    int wm = w >> 2, wn = w & 3;        // 2 x 4 wave grid

    int nbn = N >> 7;
    int rowa = (wm << 6) + (lane & 15);             // A local row (+m*16, m<4)
    int rowb = (wn << 5) + (lane & 15);             // B local row (+n*16, n<2)
    // ds_read swizzle: global chunk g = (lane>>4) | (ks<<2); row&7 == lane&7
    // (row-block offsets are multiples of 16). phys = g ^ (lane&7).
    int cswz0 = (((lane >> 4) ^ (lane & 7)) << 3);          // ks=0
    int cswz1 = ((((lane >> 4) | 4) ^ (lane & 7)) << 3);    // ks=1
    int lofs = w << 9;                  // wave's 64-slot staging region
    // staging: thread stages slots tid and tid+512 per matrix.
    // slot s: row s>>3, phys chunk s&7 -> source global chunk (s&7)^((s>>3)&7)
    int c0 = (((tid & 7) ^ ((tid >> 3) & 7)) << 3);

    for (int tix = blockIdx.x; tix < ntiles; tix += gridDim.x) {
        // XCD swizzle on tile index (ntiles % 8 == 0 here)
        int swz = (tix & 7) * (ntiles >> 3) + (tix >> 3);
        int bm = swz / nbn, bn = swz % nbn;
        int brow = bm << 7, bcol = bn << 7;

        f32x4 acc[4][2] = {};

        const short* gA0 = A + (size_t)(brow + (tid >> 3)) * K + c0;
        const short* gA1 = gA0 + (size_t)64 * K;
        const short* gB0 = Bt + (size_t)(bcol + (tid >> 3)) * K + c0;
        const short* gB1 = gB0 + (size_t)64 * K;

#define STAGE(buf, kk)                                  \
    do {                                                \
        const int buf_ = (buf);                         \
        const int kk_  = (kk);                          \
        gll16(gA0 + kk_, &As[buf_][lofs]);              \
        gll16(gA1 + kk_, &As[buf_][4096 + lofs]);       \
        gll16(gB0 + kk_, &Bs[buf_][lofs]);              \
        gll16(gB1 + kk_, &Bs[buf_][4096 + lofs]);       \
    } while (0)

// Minimal-sync K-step: ds_read issue || stage issue -> MFMA cluster (compiler
// inserts fine-grained lgkmcnt waits) -> vmcnt(0) fence -> s_barrier ->
// sched_barrier(0) (keeps next-step LDS reads below the barrier).
#define KSTEP(cur, DOSTAGE, SBUF, KKN)                                     \
    do {                                                                   \
        bf16x8 a[4][2], b[2][2];                                           \
        const short* ab = &As[cur][0];                                     \
        const short* bb = &Bs[cur][0];                                     \
        _Pragma("unroll")                                                  \
        for (int m = 0; m < 4; ++m) {                                      \
            int ro = (rowa + (m << 4)) << 6;                               \
            a[m][0] = *(const bf16x8*)&ab[ro + cswz0];                     \
            a[m][1] = *(const bf16x8*)&ab[ro + cswz1];                     \
        }                                                                  \
        _Pragma("unroll")                                                  \
        for (int n = 0; n < 2; ++n) {                                      \
            int ro = (rowb + (n << 4)) << 6;                               \
            b[n][0] = *(const bf16x8*)&bb[ro + cswz0];                     \
            b[n][1] = *(const bf16x8*)&bb[ro + cswz1];                     \
        }                                                                  \
        if (DOSTAGE) STAGE(SBUF, KKN);                                     \
        __builtin_amdgcn_s_setprio(1);                                     \
        _Pragma("unroll")                                                  \
        for (int ks = 0; ks < 2; ++ks) {                                   \
            _Pragma("unroll")                                              \
            for (int m = 0; m < 4; ++m) {                                  \
                _Pragma("unroll")                                          \
                for (int n = 0; n < 2; ++n)                                \
                    acc[m][n] = __builtin_amdgcn_mfma_f32_16x16x32_bf16(   \
                        a[m][ks], b[n][ks], acc[m][n], 0, 0, 0);           \
            }                                                              \
        }                                                                  \
        __builtin_amdgcn_s_setprio(0);                                     \
        asm volatile("s_waitcnt vmcnt(0)" ::: "memory");                   \
        __builtin_amdgcn_s_barrier();                                      \
        __builtin_amdgcn_sched_barrier(0);                                 \
    } while (0)

        int nk = K >> 6;               // 48 / 16 / 32 here (always >= 2)

        // prologue: tile 0 staged and proven landed
        STAGE(0, 0);
        asm volatile("s_waitcnt vmcnt(0)" ::: "memory");
        __builtin_amdgcn_s_barrier();
        __builtin_amdgcn_sched_barrier(0);

        for (int i = 0; i < nk; ++i) {
            KSTEP((i & 1), (i + 1 < nk), ((i + 1) & 1), ((i + 1) << 6));
        }
#undef KSTEP
#undef STAGE

        float cs[2] = {0.f, 0.f}, cs2[2] = {0.f, 0.f};
        if (OUT_BF16) {
            // ---- coalesced epilogue: wave-private LDS transpose ----
            // tp region: w*2048 shorts (4KB/wave); 8 waves = 32KB = all of As.
            short* tpb = &As[0][0] + (w << 11);
            float bv0 = bias[bcol + (wn << 5) + (lane & 15)];
            float bv1 = bias[bcol + (wn << 5) + 16 + (lane & 15)];
#pragma unroll
            for (int m = 0; m < 4; ++m) {
#pragma unroll
                for (int n = 0; n < 2; ++n) {
                    float bv = n ? bv1 : bv0;
#pragma unroll
                    for (int r = 0; r < 4; ++r) {
                        int row = (m << 4) + ((lane >> 4) << 2) + r;
                        int col = (n << 4) + (lane & 15);
                        float v = acc[m][n][r] + bv;
                        tpb[(row << 5) + col] = f2b(v);
                        if (STATS) { cs[n] += v; cs2[n] += v * v; }
                    }
                }
            }
            asm volatile("s_waitcnt lgkmcnt(0)" ::: "memory");
            __hip_bfloat16* Cb = (__hip_bfloat16*)Cout;
#pragma unroll
            for (int j = 0; j < 4; ++j) {
                int q = (j << 6) + lane;        // 0..255
                int row = q >> 2, c8 = (q & 3) << 3;
                bf16x8 vv = *(const bf16x8*)&tpb[(row << 5) + c8];
                size_t gi = (size_t)(brow + (wm << 6) + row) * N
                            + bcol + (wn << 5) + c8;
                *(bf16x8*)&Cb[gi] = vv;
            }
            __syncthreads();   // tp regions dead before sP reuse / next STAGE
        } else {
            // f32 fallback (not instantiated in this pipeline)
            int crow0 = brow + (wm << 6) + ((lane >> 4) << 2);
            int ccol0 = bcol + (wn << 5) + (lane & 15);
#pragma unroll
            for (int m = 0; m < 4; ++m) {
#pragma unroll
                for (int n = 0; n < 2; ++n) {
                    int col = ccol0 + n * 16;
                    float bv = bias[col];
#pragma unroll
                    for (int r = 0; r < 4; ++r) {
                        int row = crow0 + m * 16 + r;
                        float v = acc[m][n][r] + bv;
                        ((float*)Cout)[(size_t)row * N + col] = v;
                        if (STATS) { cs[n] += v; cs2[n] += v * v; }
                    }
                }
            }
            __syncthreads();
        }

        if (STATS) {
            float* sP = (float*)&As[0][0];   // tp regions dead (barrier above)
#pragma unroll
            for (int n = 0; n < 2; ++n) {
                float s = cs[n], s2 = cs2[n];
                s  += __shfl_xor(s, 16);  s  += __shfl_xor(s, 32);
                s2 += __shfl_xor(s2, 16); s2 += __shfl_xor(s2, 32);
                if ((lane >> 4) == 0) {
                    int c = (wn << 5) + (n << 4) + (lane & 15);   // 0..127
                    sP[wm * 128 + c] = s;
                    sP[256 + wm * 128 + c] = s2;
                }
            }
            __syncthreads();
            if (tid < 128) {
                float s = sP[tid] + sP[128 + tid];
                float s2 = sP[256 + tid] + sP[384 + tid];
                pS [(size_t)bm * N + bcol + tid] = s;
                pS2[(size_t)bm * N + bcol + tid] = s2;
            }
            __syncthreads();   // protect sP before next tile's STAGE
        }
    }
}

// ---------------------------------------------------------------------------
// BN stats reduce: 64 row-chunk partials -> per-column scale/shift
// ---------------------------------------------------------------------------
__global__ __launch_bounds__(256) void bn_stats2(
    const float* __restrict__ pS, const float* __restrict__ pS2,
    const float* __restrict__ g, const float* __restrict__ be,
    float* __restrict__ scale, float* __restrict__ shift, int ncols)
{
    int col = blockIdx.x * 256 + threadIdx.x;
    float s = 0.f, s2 = 0.f;
#pragma unroll
    for (int j = 0; j < 64; ++j) {
        s += pS[j * ncols + col];
        s2 += pS2[j * ncols + col];
    }
    float mu = s * (1.f / 8192.f);
    float var = s2 * (1.f / 8192.f) - mu * mu;
    float rs = rsqrtf(var + EPS);
    float sc = g[col] * rs;
    scale[col] = sc;
    shift[col] = be[col] - mu * sc;
}

// BN apply + ReLU, bf16 in -> bf16 out (hidden activation)
__global__ __launch_bounds__(256) void bn_apply_b2b(
    const short* __restrict__ t, const float* __restrict__ scale,
    const float* __restrict__ shift, short* __restrict__ out, int ncols)
{
    size_t i8 = (size_t)blockIdx.x * 256 + threadIdx.x;
    int col0 = (int)((i8 * 8) % ncols);
    bf16x8 v = ((const bf16x8*)t)[i8];
    bf16x8 o;
#pragma unroll
    for (int j = 0; j < 8; ++j) {
        float f = fmaxf(b2f(v[j]) * scale[col0 + j] + shift[col0 + j], 0.f);
        o[j] = f2b(f);
    }
    ((bf16x8*)out)[i8] = o;
}

// BN apply + ReLU, bf16 in -> f32 out (final, into d_out)
__global__ __launch_bounds__(256) void bn_apply_b2f(
    const short* __restrict__ t, const float* __restrict__ scale,
    const float* __restrict__ shift, float* __restrict__ out, int ncols)
{
    size_t i8 = (size_t)blockIdx.x * 256 + threadIdx.x;
    int col0 = (int)((i8 * 8) % ncols);
    bf16x8 v = ((const bf16x8*)t)[i8];
    float4 o0, o1;
    o0.x = fmaxf(b2f(v[0]) * scale[col0 + 0] + shift[col0 + 0], 0.f);
    o0.y = fmaxf(b2f(v[1]) * scale[col0 + 1] + shift[col0 + 1], 0.f);
    o0.z = fmaxf(b2f(v[2]) * scale[col0 + 2] + shift[col0 + 2], 0.f);
    o0.w = fmaxf(b2f(v[3]) * scale[col0 + 3] + shift[col0 + 3], 0.f);
    o1.x = fmaxf(b2f(v[4]) * scale[col0 + 4] + shift[col0 + 4], 0.f);
    o1.y = fmaxf(b2f(v[5]) * scale[col0 + 5] + shift[col0 + 5], 0.f);
    o1.z = fmaxf(b2f(v[6]) * scale[col0 + 6] + shift[col0 + 6], 0.f);
    o1.w = fmaxf(b2f(v[7]) * scale[col0 + 7] + shift[col0 + 7], 0.f);
    ((float4*)out)[i8 * 2]     = o0;
    ((float4*)out)[i8 * 2 + 1] = o1;
}

// ---------------------------------------------------------------------------
extern "C" void kernel_launch(void* const* d_in, const int* in_sizes, int n_in,
                              void* d_out, int out_size, void* d_ws, size_t ws_size,
                              hipStream_t stream)
{
    const float* selfv = (const float*)d_in[0];   // [32,256,1024]
    const float* nbv   = (const float*)d_in[1];   // [32,256,8,2048]
    const float* mask  = (const float*)d_in[2];   // [32,256,8,1]
    const float* W_agg = (const float*)d_in[3];   // [3072,1024]
    const float* b_agg = (const float*)d_in[4];   // [1024]
    const float* W1    = (const float*)d_in[5];   // [1024,2048]
    const float* b1    = (const float*)d_in[6];   // [2048]
    const float* g1    = (const float*)d_in[7];
    const float* be1   = (const float*)d_in[8];
    const float* W2    = (const float*)d_in[9];   // [2048,1024]
    const float* b2    = (const float*)d_in[10];
    const float* g2    = (const float*)d_in[11];
    const float* be2   = (const float*)d_in[12];

    char* ws = (char*)d_ws;
    const size_t MiB = 1ull << 20;
    __hip_bfloat16* h    = (__hip_bfloat16*)(ws + 0);          // [8192,1024] bf16, 16 MiB
    __hip_bfloat16* xb   = (__hip_bfloat16*)(ws + 16 * MiB);   // [8192,3072] bf16, 48 MiB
    __hip_bfloat16* t1b  = (__hip_bfloat16*)(ws + 16 * MiB);   // [8192,2048] bf16, 32 MiB
    __hip_bfloat16* h1   = (__hip_bfloat16*)(ws + 80 * MiB);   // [8192,2048] bf16, 32 MiB
    __hip_bfloat16* WaggT= (__hip_bfloat16*)(ws + 112 * MiB);  // [1024,3072] bf16, 6 MiB
    __hip_bfloat16* W1T  = (__hip_bfloat16*)(ws + 118 * MiB);  // [2048,1024] bf16, 4 MiB
    __hip_bfloat16* W2T  = (__hip_bfloat16*)(ws + 122 * MiB);  // [1024,2048] bf16, 4 MiB
    float* pS     = (float*)(ws + 126 * MiB);                   // [64,2048] partials
    float* pS2    = (float*)(ws + 126 * MiB + 512 * 1024);
    float* scale1 = (float*)(ws + 127 * MiB);
    float* shift1 = scale1 + 2048;
    float* scale2 = shift1 + 2048;
    float* shift2 = scale2 + 1024;
    __hip_bfloat16* t2b = h;   // [8192,1024] bf16 (h is dead after GEMM2)

    // merged prep: build_x (blocks 0..8191) + 3 weight transposes (rest)
    prep<<<ROWS + 7168, 256, 0, stream>>>(
        selfv, nbv, mask, xb, W_agg, WaggT, W1, W1T, W2, W2T);

    // GEMM1: h = x @ W_agg + b_agg   (bf16 out, no stats)
    gemm_bt<1, 0><<<512, 512, 0, stream>>>(
        (const short*)xb, (const short*)WaggT, b_agg, h, nullptr, nullptr,
        ROWS, OUTC, XCOLS, 512);

    // GEMM2: t1b = h @ W1 + b1  (bf16 out + BN1 partials)
    gemm_bt<1, 1><<<1024, 512, 0, stream>>>(
        (const short*)h, (const short*)W1T, b1, t1b, pS, pS2, ROWS, HIDC, OUTC, 1024);

    // BN1 reduce + apply + ReLU -> h1 (bf16)
    bn_stats2<<<HIDC / 256, 256, 0, stream>>>(pS, pS2, g1, be1, scale1, shift1, HIDC);
    bn_apply_b2b<<<(ROWS * HIDC) / 2048, 256, 0, stream>>>(
        (const short*)t1b, scale1, shift1, (short*)h1, HIDC);

    // GEMM3: t2b = h1 @ W2 + b2  (bf16 out + BN2 partials)
    gemm_bt<1, 1><<<512, 512, 0, stream>>>(
        (const short*)h1, (const short*)W2T, b2, t2b, pS, pS2, ROWS, OUTC, HIDC, 512);

    // BN2 reduce + apply + ReLU -> d_out (f32)
    bn_stats2<<<OUTC / 256, 256, 0, stream>>>(pS, pS2, g2, be2, scale2, shift2, OUTC);
    bn_apply_b2f<<<(ROWS * OUTC) / 2048, 256, 0, stream>>>(
        (const short*)t2b, scale2, shift2, (float*)d_out, OUTC);
}